// Round 16
// baseline (209.262 us; speedup 1.0000x reference)
//
#include <hip/hip_runtime.h>
#include <hip/hip_bf16.h>

#define B_ 128
#define E_ 300
#define C_ 5
#define NODES 2047

typedef __attribute__((ext_vector_type(8))) short short8;
typedef __attribute__((ext_vector_type(4))) float f32x4;
typedef __hip_bfloat16 bf16;

__device__ __forceinline__ short f2bs(float v) {
  bf16 b = (bf16)v;
  return *reinterpret_cast<short*>(&b);
}

__device__ __forceinline__ short8 pack_relu(f32x4 v0, f32x4 v1) {
  short8 s;
#pragma unroll
  for (int j = 0; j < 4; j++) s[j] = f2bs(fmaxf(v0[j], 0.f));
#pragma unroll
  for (int j = 0; j < 4; j++) s[4 + j] = f2bs(fmaxf(v1[j], 0.f));
  return s;
}

// LDS out-tile: row stride 312 elems (624 B), no skew; 304 data cols fit.
#define HSROW(base, r) ((base) + (r) * 312)

// proj fragment mask: cols 304..319 don't exist in the 304-wide tile;
// Ppf is zero there, so zero-substitution is exact.
#define PROJ_A(rowptr, ks, k0)                               \
  ((ks) == 9 && half >= 2 ? (short8){0, 0, 0, 0, 0, 0, 0, 0} \
                          : *(const short8*)((rowptr) + (k0)))

// ---------------------------------------------------------------------------
// Prep: T[V][304] = bf16(relu(emb)) (streaming) + fragment-major weights.
// ---------------------------------------------------------------------------
__global__ __launch_bounds__(256) void prep_k(
    const float* __restrict__ emb, const float* __restrict__ Ww,
    const float* __restrict__ Pw, bf16* __restrict__ T, bf16* __restrict__ Wf,
    bf16* __restrict__ Pqf, bf16* __restrict__ Ppf, int V) {
  int idx = blockIdx.x * 256 + threadIdx.x;
  int tchunks = V * 38;
  if (idx < tchunks) {
    int v = idx / 38, c = idx % 38;
    const float* src = emb + (size_t)v * E_ + c * 8;
    f32x4 v0 = *(const f32x4*)src;
    f32x4 v1 = (c == 37) ? (f32x4){0.f, 0.f, 0.f, 0.f}
                         : *(const f32x4*)(src + 4);
    *(short8*)(T + (size_t)v * 304 + c * 8) = pack_relu(v0, v1);
  }
  if (idx < 20 * 19 * 64) {
    int wnt = idx / 1216, rem = idx % 1216;
    int ks = rem >> 6, l = rem & 63;
    int n = wnt * 16 + (l & 15);
    int k0 = ks * 32 + (l >> 4) * 8;
    short8 v;
#pragma unroll
    for (int j = 0; j < 8; j++) {
      int k = k0 + j;
      float x = 0.f;
      if (n < E_) {
        if (k < E_) x = Ww[n * 600 + k];
        else if (k >= 304 && k < 604) x = Ww[n * 600 + k - 4];
      }
      v[j] = f2bs(x);
    }
    *(short8*)(Wf + (size_t)idx * 8) = v;
  }
  if (idx < 2 * 19 * 64) {
    int p = idx / 1216, rem = idx % 1216;
    int ks = rem >> 6, l = rem & 63;
    int q = l & 15;
    int k0 = ks * 32 + (l >> 4) * 8;
    short8 v;
#pragma unroll
    for (int j = 0; j < 8; j++) {
      int e = k0 + j - 304 * p;
      float x = (q < C_ && e >= 0 && e < E_) ? Pw[q * E_ + e] : 0.f;
      v[j] = f2bs(x);
    }
    *(short8*)(Pqf + (size_t)idx * 8) = v;
  }
  if (idx < 10 * 64) {
    int ks = idx >> 6, l = idx & 63;
    int q = l & 15;
    int k0 = ks * 32 + (l >> 4) * 8;
    short8 v;
#pragma unroll
    for (int j = 0; j < 8; j++) {
      int e = k0 + j;
      float x = (q < C_ && e < E_) ? Pw[q * E_ + e] : 0.f;
      v[j] = f2bs(x);
    }
    *(short8*)(Ppf + (size_t)idx * 8) = v;
  }
}

// ---------------------------------------------------------------------------
// Fused level 1 (r12 structure, pinned at ~75.5 us): BM=64 out rows,
// grid 1024, 8 waves. wg=w&3: col group; wh=w>>2: row-tiles {2wh,2wh+1}.
// ---------------------------------------------------------------------------
__global__ __launch_bounds__(512, 2) void fused_l1_k(
    const int* __restrict__ wid, const bf16* __restrict__ T,
    const bf16* __restrict__ Wf, const float* __restrict__ Wb,
    const bf16* __restrict__ Pqf, const bf16* __restrict__ Ppf,
    const float* __restrict__ Pb, bf16* __restrict__ h1f,
    float* __restrict__ out) {
  __shared__ short ldsA[64 * 616 + 64];
  int tid = threadIdx.x;
  int m0 = blockIdx.x * 64;

  for (int i = tid; i < 64 * 76; i += 512) {
    int r = i / 76, c2 = i % 76;
    int par = c2 >= 38 ? 1 : 0;
    int c = c2 - 38 * par;
    int word = wid[2 * (m0 + r) + par];
    short8 v = *(const short8*)(T + (size_t)word * 304 + c * 8);
    *(short8*)&ldsA[r * 616 + par * 304 + c * 8] = v;
  }
  __syncthreads();

  int w = tid >> 6, l = tid & 63, q = l & 15, half = l >> 4;
  int wg = w & 3, wh = w >> 2;
  int ab0 = ((wh * 2 + 0) * 16 + q) * 616;
  int ab1 = ((wh * 2 + 1) * 16 + q) * 616;
  int abL = ((w & 3) * 16 + q) * 616;  // leaf-proj A row (tile w&3)
  int pL = w >> 2;                     // leaf-proj parity

  f32x4 acc[2][5];
#pragma unroll
  for (int rt = 0; rt < 2; rt++)
#pragma unroll
    for (int nt = 0; nt < 5; nt++) acc[rt][nt] = (f32x4){0.f, 0.f, 0.f, 0.f};
  f32x4 pacc = (f32x4){0.f, 0.f, 0.f, 0.f};

#pragma unroll 2
  for (int ks = 0; ks < 19; ks++) {
    int k0 = ks * 32 + half * 8;
    short8 a0 = *(const short8*)&ldsA[ab0 + k0];
    short8 a1 = *(const short8*)&ldsA[ab1 + k0];
    short8 al = *(const short8*)&ldsA[abL + k0];
    short8 pq = *(const short8*)(Pqf + ((size_t)(pL * 19 + ks) * 64 + l) * 8);
    pacc = __builtin_amdgcn_mfma_f32_16x16x32_bf16(al, pq, pacc, 0, 0, 0);
#pragma unroll
    for (int nt = 0; nt < 5; nt++) {
      short8 b = *(const short8*)(Wf +
          ((size_t)((5 * wg + nt) * 19 + ks) * 64 + l) * 8);
      acc[0][nt] =
          __builtin_amdgcn_mfma_f32_16x16x32_bf16(a0, b, acc[0][nt], 0, 0, 0);
      acc[1][nt] =
          __builtin_amdgcn_mfma_f32_16x16x32_bf16(a1, b, acc[1][nt], 0, 0, 0);
    }
  }
  __syncthreads();  // staging reads done; reuse ldsA as out-tile t1

  // epilogue lvl1 -> t1
#pragma unroll
  for (int nt = 0; nt < 5; nt++) {
    int n = wg * 80 + nt * 16 + q;
    float wb = (n < E_) ? Wb[n] : 0.f;
    if (n < 304) {
#pragma unroll
      for (int rt = 0; rt < 2; rt++)
#pragma unroll
        for (int j = 0; j < 4; j++) {
          int rl = (wh * 2 + rt) * 16 + half * 4 + j;
          HSROW(ldsA, rl)[n] = f2bs(fmaxf(acc[rt][nt][j] + wb, 0.f));
        }
    }
  }
  // leaf logits: wave w -> (row-tile w&3, parity w>>2)
  if (q < C_) {
    float pb = Pb[q];
#pragma unroll
    for (int j = 0; j < 4; j++) {
      int row = m0 + (w & 3) * 16 + half * 4 + j;
      int leaf = 2 * row + pL;
      out[((size_t)(leaf >> 10) * NODES + (leaf & 1023)) * C_ + q] =
          pacc[j] + pb;
    }
  }
  __syncthreads();  // t1 complete

  // frag-store h1 (2 g-tiles per block)
  for (int i = tid; i < 2 * 19 * 64; i += 512) {
    int gl = i / 1216, rem = i % 1216;
    int ks = rem >> 6, ll = rem & 63;
    int qq = ll & 15, hh = ll >> 4;
    int k0 = ks * 32 + hh * 8;
    int sel = k0 >= 304 ? 1 : 0;
    int e = k0 - 304 * sel;
    int lr = 2 * (gl * 16 + qq) + sel;
    short8 v = *(const short8*)&HSROW(ldsA, lr)[e];
    *(short8*)(h1f + (((size_t)((m0 >> 5) + gl) * 19 + ks) * 64 + ll) * 8) = v;
  }
  // L1 projection: waves 0..3, rows [16w, 16w+16)
  if (w < 4) {
    f32x4 pc = (f32x4){0.f, 0.f, 0.f, 0.f};
#pragma unroll
    for (int ks = 0; ks < 10; ks++) {
      int k0 = ks * 32 + half * 8;
      short8 a = PROJ_A(HSROW(ldsA, 16 * w + q), ks, k0);
      short8 b = *(const short8*)(Ppf + ((size_t)ks * 64 + l) * 8);
      pc = __builtin_amdgcn_mfma_f32_16x16x32_bf16(a, b, pc, 0, 0, 0);
    }
    if (q < C_) {
      float pb = Pb[q];
#pragma unroll
      for (int j = 0; j < 4; j++) {
        int m = m0 + w * 16 + half * 4 + j;
        out[((size_t)(m >> 9) * NODES + 1024 + (m & 511)) * C_ + q] =
            pc[j] + pb;
      }
    }
  }
}

// ---------------------------------------------------------------------------
// Staged combine (levels 2..5): A chunks staged to LDS as a LINEAR copy of
// the frag-major layout (lane-linear ds_read = conflict-free; coalesced
// stage). Kills the 4x duplicated A TA-requests of the global-A version.
// Out-tile overlays the A region after a barrier (fused_l1's pattern).
// ---------------------------------------------------------------------------
template <int RT>
__global__ __launch_bounds__(512, 2) void combine_s(
    const bf16* __restrict__ hin_f, const bf16* __restrict__ Wf,
    const float* __restrict__ Wb, const bf16* __restrict__ Ppf,
    const float* __restrict__ Pb, bf16* __restrict__ hout_f,
    float* __restrict__ out, int node_off, int nshift) {
  const int HR = RT / 2;  // row-tiles per wave
  __shared__ short lds[RT * 1216 * 8 + 32];  // A chunks; later out-tile
  int tid = threadIdx.x;
  int m0 = blockIdx.x * (RT * 16);
  int g0b = m0 >> 4;  // first A g-tile of this block

  // stage A: RT*1216 chunks, linear copy (coalesced both sides)
  for (int i = tid; i < RT * 1216; i += 512) {
    *(short8*)&lds[i * 8] =
        *(const short8*)(hin_f + ((size_t)g0b * 1216 + i) * 8);
  }
  __syncthreads();

  int w = tid >> 6, l = tid & 63, q = l & 15, half = l >> 4;
  int wg = w & 3, wh = w >> 2;

  f32x4 acc[HR][5];
#pragma unroll
  for (int rt = 0; rt < HR; rt++)
#pragma unroll
    for (int nt = 0; nt < 5; nt++) acc[rt][nt] = (f32x4){0.f, 0.f, 0.f, 0.f};

#pragma unroll 2
  for (int ks = 0; ks < 19; ks++) {
    short8 a[HR];
#pragma unroll
    for (int rt = 0; rt < HR; rt++) {
      int rtb = wh * HR + rt;  // row-tile within block
      a[rt] = *(const short8*)&lds[((rtb * 19 + ks) * 64 + l) * 8];
    }
#pragma unroll
    for (int nt = 0; nt < 5; nt++) {
      short8 b = *(const short8*)(Wf +
          ((size_t)((5 * wg + nt) * 19 + ks) * 64 + l) * 8);
#pragma unroll
      for (int rt = 0; rt < HR; rt++)
        acc[rt][nt] = __builtin_amdgcn_mfma_f32_16x16x32_bf16(
            a[rt], b, acc[rt][nt], 0, 0, 0);
    }
  }
  __syncthreads();  // all A reads done; overlay out-tile on lds

#pragma unroll
  for (int nt = 0; nt < 5; nt++) {
    int n = wg * 80 + nt * 16 + q;
    float wb = (n < E_) ? Wb[n] : 0.f;
    if (n < 304) {
#pragma unroll
      for (int rt = 0; rt < HR; rt++)
#pragma unroll
        for (int j = 0; j < 4; j++) {
          int rl = (wh * HR + rt) * 16 + half * 4 + j;
          HSROW(lds, rl)[n] = f2bs(fmaxf(acc[rt][nt][j] + wb, 0.f));
        }
    }
  }
  __syncthreads();  // out-tile complete

  // frag-store: RT/2 g-tiles of 32 rows per block
  for (int i = tid; i < (RT / 2) * 1216; i += 512) {
    int gl = i / 1216, rem = i % 1216;
    int ks = rem >> 6, ll = rem & 63;
    int qq = ll & 15, hh = ll >> 4;
    int k0 = ks * 32 + hh * 8;
    int sel = k0 >= 304 ? 1 : 0;
    int e = k0 - 304 * sel;
    int lr = 2 * (gl * 16 + qq) + sel;
    short8 v = *(const short8*)&HSROW(lds, lr)[e];
    *(short8*)(hout_f +
               (((size_t)((m0 >> 5) + gl) * 19 + ks) * 64 + ll) * 8) = v;
  }
  // projection: waves 0..RT-1, rows [16w, 16w+16)
  if (w < RT) {
    f32x4 pacc = (f32x4){0.f, 0.f, 0.f, 0.f};
#pragma unroll
    for (int ks = 0; ks < 10; ks++) {
      int k0 = ks * 32 + half * 8;
      short8 a = PROJ_A(HSROW(lds, 16 * w + q), ks, k0);
      short8 b = *(const short8*)(Ppf + ((size_t)ks * 64 + l) * 8);
      pacc = __builtin_amdgcn_mfma_f32_16x16x32_bf16(a, b, pacc, 0, 0, 0);
    }
    if (q < C_) {
      float pb = Pb[q];
#pragma unroll
      for (int j = 0; j < 4; j++) {
        size_t m = m0 + w * 16 + half * 4 + j;
        size_t b_ = m >> nshift;
        size_t n = m & (((size_t)1 << nshift) - 1);
        out[((size_t)b_ * NODES + node_off + n) * C_ + q] = pacc[j] + pb;
      }
    }
  }
}

// ---------------------------------------------------------------------------
// Global-A combine (levels 6..10, tiny grids: minimal barriers).
// ---------------------------------------------------------------------------
template <int RT>
__global__ __launch_bounds__(512, 2) void combine_k(
    const bf16* __restrict__ hin_f, const bf16* __restrict__ Wf,
    const float* __restrict__ Wb, const bf16* __restrict__ Ppf,
    const float* __restrict__ Pb, bf16* __restrict__ hout_f,
    float* __restrict__ out, int node_off, int nshift) {
  const int HR = RT / 2;
  __shared__ short hsO[RT * 16 * 312 + 64];
  int tid = threadIdx.x;
  int w = tid >> 6, l = tid & 63, q = l & 15, half = l >> 4;
  int wg = w & 3, wh = w >> 2;
  int m0 = blockIdx.x * (RT * 16);
  int g0 = (m0 >> 4) + wh * HR;

  f32x4 acc[HR][5];
#pragma unroll
  for (int rt = 0; rt < HR; rt++)
#pragma unroll
    for (int nt = 0; nt < 5; nt++) acc[rt][nt] = (f32x4){0.f, 0.f, 0.f, 0.f};

#pragma unroll 2
  for (int ks = 0; ks < 19; ks++) {
    short8 a[HR];
#pragma unroll
    for (int rt = 0; rt < HR; rt++)
      a[rt] = *(const short8*)(hin_f +
          (((size_t)(g0 + rt) * 19 + ks) * 64 + l) * 8);
#pragma unroll
    for (int nt = 0; nt < 5; nt++) {
      short8 b = *(const short8*)(Wf +
          ((size_t)((5 * wg + nt) * 19 + ks) * 64 + l) * 8);
#pragma unroll
      for (int rt = 0; rt < HR; rt++)
        acc[rt][nt] = __builtin_amdgcn_mfma_f32_16x16x32_bf16(
            a[rt], b, acc[rt][nt], 0, 0, 0);
    }
  }

#pragma unroll
  for (int nt = 0; nt < 5; nt++) {
    int n = wg * 80 + nt * 16 + q;
    float wb = (n < E_) ? Wb[n] : 0.f;
    if (n < 304) {
#pragma unroll
      for (int rt = 0; rt < HR; rt++)
#pragma unroll
        for (int j = 0; j < 4; j++) {
          int rl = (wh * HR + rt) * 16 + half * 4 + j;
          HSROW(hsO, rl)[n] = f2bs(fmaxf(acc[rt][nt][j] + wb, 0.f));
        }
    }
  }
  __syncthreads();

  for (int i = tid; i < (RT / 2) * 1216; i += 512) {
    int gl = i / 1216, rem = i % 1216;
    int ks = rem >> 6, ll = rem & 63;
    int qq = ll & 15, hh = ll >> 4;
    int k0 = ks * 32 + hh * 8;
    int sel = k0 >= 304 ? 1 : 0;
    int e = k0 - 304 * sel;
    int lr = 2 * (gl * 16 + qq) + sel;
    short8 v = *(const short8*)&HSROW(hsO, lr)[e];
    *(short8*)(hout_f +
               (((size_t)((m0 >> 5) + gl) * 19 + ks) * 64 + ll) * 8) = v;
  }
  if (w < RT) {
    f32x4 pacc = (f32x4){0.f, 0.f, 0.f, 0.f};
#pragma unroll
    for (int ks = 0; ks < 10; ks++) {
      int k0 = ks * 32 + half * 8;
      short8 a = PROJ_A(HSROW(hsO, 16 * w + q), ks, k0);
      short8 b = *(const short8*)(Ppf + ((size_t)ks * 64 + l) * 8);
      pacc = __builtin_amdgcn_mfma_f32_16x16x32_bf16(a, b, pacc, 0, 0, 0);
    }
    if (q < C_) {
      float pb = Pb[q];
#pragma unroll
      for (int j = 0; j < 4; j++) {
        size_t m = m0 + w * 16 + half * 4 + j;
        size_t b_ = m >> nshift;
        size_t n = m & (((size_t)1 << nshift) - 1);
        out[((size_t)b_ * NODES + node_off + n) * C_ + q] = pacc[j] + pb;
      }
    }
  }
}

// ---------------------------------------------------------------------------
extern "C" void kernel_launch(void* const* d_in, const int* in_sizes, int n_in,
                              void* d_out, int out_size, void* d_ws,
                              size_t ws_size, hipStream_t stream) {
  const int* wid = (const int*)d_in[0];
  const float* emb = (const float*)d_in[1];
  const float* Ww = (const float*)d_in[2];
  const float* Wb = (const float*)d_in[3];
  const float* Pw = (const float*)d_in[4];
  const float* Pb = (const float*)d_in[5];
  float* out = (float*)d_out;
  int V = in_sizes[1] / E_;  // 50000

  bf16* hA = (bf16*)d_ws;                     // h1f, h3f, h5f, h7f, h9f
  bf16* hB = hA + (size_t)B_ * 512 * 304;     // h2f, h4f, h6f, h8f, h10f
  bf16* Wf = hB + (size_t)B_ * 256 * 304;
  bf16* Pqf = Wf + (size_t)20 * 19 * 512;
  bf16* Ppf = Pqf + (size_t)2 * 19 * 512;
  bf16* T = Ppf + (size_t)10 * 512;           // V * 304 (30.4 MB)

  int tchunks = V * 38;
  prep_k<<<(tchunks + 255) / 256, 256, 0, stream>>>(emb, Ww, Pw, T, Wf, Pqf,
                                                    Ppf, V);
  fused_l1_k<<<1024, 512, 0, stream>>>(wid, T, Wf, Wb, Pqf, Ppf, Pb, hA, out);
  // lvl2..5: M = 32768, 16384, 8192, 4096  (staged-A combine)
  combine_s<4><<<512, 512, 0, stream>>>(hA, Wf, Wb, Ppf, Pb, hB, out, 1536, 8);
  combine_s<4><<<256, 512, 0, stream>>>(hB, Wf, Wb, Ppf, Pb, hA, out, 1792, 7);
  combine_s<2><<<256, 512, 0, stream>>>(hA, Wf, Wb, Ppf, Pb, hB, out, 1920, 6);
  combine_s<2><<<128, 512, 0, stream>>>(hB, Wf, Wb, Ppf, Pb, hA, out, 1984, 5);
  // lvl6..10: M = 2048, 1024, 512, 256, 128  (global-A, minimal barriers)
  combine_k<2><<<64, 512, 0, stream>>>(hA, Wf, Wb, Ppf, Pb, hB, out, 2016, 4);
  combine_k<2><<<32, 512, 0, stream>>>(hB, Wf, Wb, Ppf, Pb, hA, out, 2032, 3);
  combine_k<2><<<16, 512, 0, stream>>>(hA, Wf, Wb, Ppf, Pb, hB, out, 2040, 2);
  combine_k<2><<<8, 512, 0, stream>>>(hB, Wf, Wb, Ppf, Pb, hA, out, 2044, 1);
  combine_k<2><<<4, 512, 0, stream>>>(hA, Wf, Wb, Ppf, Pb, hB, out, 2046, 0);
}

// Round 17
// 202.576 us; speedup vs baseline: 1.0330x; 1.0330x over previous
//
#include <hip/hip_runtime.h>
#include <hip/hip_bf16.h>

#define B_ 128
#define E_ 300
#define C_ 5
#define NODES 2047

typedef __attribute__((ext_vector_type(8))) short short8;
typedef __attribute__((ext_vector_type(4))) float f32x4;
typedef __hip_bfloat16 bf16;

__device__ __forceinline__ short f2bs(float v) {
  bf16 b = (bf16)v;
  return *reinterpret_cast<short*>(&b);
}

__device__ __forceinline__ short8 pack_relu(f32x4 v0, f32x4 v1) {
  short8 s;
#pragma unroll
  for (int j = 0; j < 4; j++) s[j] = f2bs(fmaxf(v0[j], 0.f));
#pragma unroll
  for (int j = 0; j < 4; j++) s[4 + j] = f2bs(fmaxf(v1[j], 0.f));
  return s;
}

// LDS out-tile: row stride 312 elems (624 B), no skew; 304 data cols fit.
#define HSROW(base, r) ((base) + (r) * 312)

// proj fragment mask: cols 304..319 don't exist in the 304-wide tile;
// Ppf is zero there, so zero-substitution is exact.
#define PROJ_A(rowptr, ks, k0)                               \
  ((ks) == 9 && half >= 2 ? (short8){0, 0, 0, 0, 0, 0, 0, 0} \
                          : *(const short8*)((rowptr) + (k0)))

// ---------------------------------------------------------------------------
// Prep: T[V][304] = bf16(relu(emb)) (streaming) + fragment-major weights.
//  Wfrag chunks idx=(wnt*19+ks)*64+l; chunk[j]: row=16wnt+(l&15),
//  k=32ks+8(l>>4)+j (pair-k). Pqf: leaf-proj (2 parities); Ppf: node proj.
// ---------------------------------------------------------------------------
__global__ __launch_bounds__(256) void prep_k(
    const float* __restrict__ emb, const float* __restrict__ Ww,
    const float* __restrict__ Pw, bf16* __restrict__ T, bf16* __restrict__ Wf,
    bf16* __restrict__ Pqf, bf16* __restrict__ Ppf, int V) {
  int idx = blockIdx.x * 256 + threadIdx.x;
  int tchunks = V * 38;
  if (idx < tchunks) {
    int v = idx / 38, c = idx % 38;
    const float* src = emb + (size_t)v * E_ + c * 8;
    f32x4 v0 = *(const f32x4*)src;
    f32x4 v1 = (c == 37) ? (f32x4){0.f, 0.f, 0.f, 0.f}
                         : *(const f32x4*)(src + 4);
    *(short8*)(T + (size_t)v * 304 + c * 8) = pack_relu(v0, v1);
  }
  if (idx < 20 * 19 * 64) {
    int wnt = idx / 1216, rem = idx % 1216;
    int ks = rem >> 6, l = rem & 63;
    int n = wnt * 16 + (l & 15);
    int k0 = ks * 32 + (l >> 4) * 8;
    short8 v;
#pragma unroll
    for (int j = 0; j < 8; j++) {
      int k = k0 + j;
      float x = 0.f;
      if (n < E_) {
        if (k < E_) x = Ww[n * 600 + k];
        else if (k >= 304 && k < 604) x = Ww[n * 600 + k - 4];
      }
      v[j] = f2bs(x);
    }
    *(short8*)(Wf + (size_t)idx * 8) = v;
  }
  if (idx < 2 * 19 * 64) {
    int p = idx / 1216, rem = idx % 1216;
    int ks = rem >> 6, l = rem & 63;
    int q = l & 15;
    int k0 = ks * 32 + (l >> 4) * 8;
    short8 v;
#pragma unroll
    for (int j = 0; j < 8; j++) {
      int e = k0 + j - 304 * p;
      float x = (q < C_ && e >= 0 && e < E_) ? Pw[q * E_ + e] : 0.f;
      v[j] = f2bs(x);
    }
    *(short8*)(Pqf + (size_t)idx * 8) = v;
  }
  if (idx < 10 * 64) {
    int ks = idx >> 6, l = idx & 63;
    int q = l & 15;
    int k0 = ks * 32 + (l >> 4) * 8;
    short8 v;
#pragma unroll
    for (int j = 0; j < 8; j++) {
      int e = k0 + j;
      float x = (q < C_ && e < E_) ? Pw[q * E_ + e] : 0.f;
      v[j] = f2bs(x);
    }
    *(short8*)(Ppf + (size_t)idx * 8) = v;
  }
}

// ---------------------------------------------------------------------------
// Fused level 1: BM=64 out rows (=128 leaves), grid 1024, 8 waves (512 thr).
// wg = w&3: col group [80wg, 80wg+80); wh = w>>2: row-tiles {2wh, 2wh+1}.
// Leaf projection: wave w owns (row-tile w&3, parity w>>2) — one ds_read +
// one Pqf load + one MFMA per ks, no cross-register select.
// Stage bf16 T rows -> LDS; A via ds_read_b128; B/Pq frag-major coalesced.
// ---------------------------------------------------------------------------
__global__ __launch_bounds__(512, 2) void fused_l1_k(
    const int* __restrict__ wid, const bf16* __restrict__ T,
    const bf16* __restrict__ Wf, const float* __restrict__ Wb,
    const bf16* __restrict__ Pqf, const bf16* __restrict__ Ppf,
    const float* __restrict__ Pb, bf16* __restrict__ h1f,
    float* __restrict__ out) {
  __shared__ short ldsA[64 * 616 + 64];
  int tid = threadIdx.x;
  int m0 = blockIdx.x * 64;

  for (int i = tid; i < 64 * 76; i += 512) {
    int r = i / 76, c2 = i % 76;
    int par = c2 >= 38 ? 1 : 0;
    int c = c2 - 38 * par;
    int word = wid[2 * (m0 + r) + par];
    short8 v = *(const short8*)(T + (size_t)word * 304 + c * 8);
    *(short8*)&ldsA[r * 616 + par * 304 + c * 8] = v;
  }
  __syncthreads();

  int w = tid >> 6, l = tid & 63, q = l & 15, half = l >> 4;
  int wg = w & 3, wh = w >> 2;
  int ab0 = ((wh * 2 + 0) * 16 + q) * 616;
  int ab1 = ((wh * 2 + 1) * 16 + q) * 616;
  int abL = ((w & 3) * 16 + q) * 616;  // leaf-proj A row (tile w&3)
  int pL = w >> 2;                     // leaf-proj parity

  f32x4 acc[2][5];
#pragma unroll
  for (int rt = 0; rt < 2; rt++)
#pragma unroll
    for (int nt = 0; nt < 5; nt++) acc[rt][nt] = (f32x4){0.f, 0.f, 0.f, 0.f};
  f32x4 pacc = (f32x4){0.f, 0.f, 0.f, 0.f};

#pragma unroll 2
  for (int ks = 0; ks < 19; ks++) {
    int k0 = ks * 32 + half * 8;
    short8 a0 = *(const short8*)&ldsA[ab0 + k0];
    short8 a1 = *(const short8*)&ldsA[ab1 + k0];
    short8 al = *(const short8*)&ldsA[abL + k0];
    short8 pq = *(const short8*)(Pqf + ((size_t)(pL * 19 + ks) * 64 + l) * 8);
    pacc = __builtin_amdgcn_mfma_f32_16x16x32_bf16(al, pq, pacc, 0, 0, 0);
#pragma unroll
    for (int nt = 0; nt < 5; nt++) {
      short8 b = *(const short8*)(Wf +
          ((size_t)((5 * wg + nt) * 19 + ks) * 64 + l) * 8);
      acc[0][nt] =
          __builtin_amdgcn_mfma_f32_16x16x32_bf16(a0, b, acc[0][nt], 0, 0, 0);
      acc[1][nt] =
          __builtin_amdgcn_mfma_f32_16x16x32_bf16(a1, b, acc[1][nt], 0, 0, 0);
    }
  }
  __syncthreads();  // staging reads done; reuse ldsA as out-tile t1

  // epilogue lvl1 -> t1
#pragma unroll
  for (int nt = 0; nt < 5; nt++) {
    int n = wg * 80 + nt * 16 + q;
    float wb = (n < E_) ? Wb[n] : 0.f;
    if (n < 304) {
#pragma unroll
      for (int rt = 0; rt < 2; rt++)
#pragma unroll
        for (int j = 0; j < 4; j++) {
          int rl = (wh * 2 + rt) * 16 + half * 4 + j;
          HSROW(ldsA, rl)[n] = f2bs(fmaxf(acc[rt][nt][j] + wb, 0.f));
        }
    }
  }
  // leaf logits: wave w -> (row-tile w&3, parity w>>2)
  if (q < C_) {
    float pb = Pb[q];
#pragma unroll
    for (int j = 0; j < 4; j++) {
      int row = m0 + (w & 3) * 16 + half * 4 + j;
      int leaf = 2 * row + pL;
      out[((size_t)(leaf >> 10) * NODES + (leaf & 1023)) * C_ + q] =
          pacc[j] + pb;
    }
  }
  __syncthreads();  // t1 complete

  // frag-store h1 (2 g-tiles per block)
  for (int i = tid; i < 2 * 19 * 64; i += 512) {
    int gl = i / 1216, rem = i % 1216;
    int ks = rem >> 6, ll = rem & 63;
    int qq = ll & 15, hh = ll >> 4;
    int k0 = ks * 32 + hh * 8;
    int sel = k0 >= 304 ? 1 : 0;
    int e = k0 - 304 * sel;
    int lr = 2 * (gl * 16 + qq) + sel;
    short8 v = *(const short8*)&HSROW(ldsA, lr)[e];
    *(short8*)(h1f + (((size_t)((m0 >> 5) + gl) * 19 + ks) * 64 + ll) * 8) = v;
  }
  // L1 projection: waves 0..3, rows [16w, 16w+16)
  if (w < 4) {
    f32x4 pc = (f32x4){0.f, 0.f, 0.f, 0.f};
#pragma unroll
    for (int ks = 0; ks < 10; ks++) {
      int k0 = ks * 32 + half * 8;
      short8 a = PROJ_A(HSROW(ldsA, 16 * w + q), ks, k0);
      short8 b = *(const short8*)(Ppf + ((size_t)ks * 64 + l) * 8);
      pc = __builtin_amdgcn_mfma_f32_16x16x32_bf16(a, b, pc, 0, 0, 0);
    }
    if (q < C_) {
      float pb = Pb[q];
#pragma unroll
      for (int j = 0; j < 4; j++) {
        int m = m0 + w * 16 + half * 4 + j;
        out[((size_t)(m >> 9) * NODES + 1024 + (m & 511)) * C_ + q] =
            pc[j] + pb;
      }
    }
  }
}

// ---------------------------------------------------------------------------
// Combine (levels 2..10): 512 threads, 8 waves, BM = 16*RT.
// wg = w&3: col group; wh = w>>2: row-half (RT/2 g-tiles each). Wave pairs
// with equal wg re-hit the same Wf lines (L1). VGPR cap 128 (no spill).
// A/B fully coalesced fragment-major global loads; no main-loop barriers.
// ---------------------------------------------------------------------------
template <int RT>
__global__ __launch_bounds__(512, 2) void combine_k(
    const bf16* __restrict__ hin_f, const bf16* __restrict__ Wf,
    const float* __restrict__ Wb, const bf16* __restrict__ Ppf,
    const float* __restrict__ Pb, bf16* __restrict__ hout_f,
    float* __restrict__ out, int node_off, int nshift) {
  const int HR = RT / 2;  // row-tiles per wave-half
  __shared__ short hsO[RT * 16 * 312 + 64];
  int tid = threadIdx.x;
  int w = tid >> 6, l = tid & 63, q = l & 15, half = l >> 4;
  int wg = w & 3, wh = w >> 2;
  int m0 = blockIdx.x * (RT * 16);
  int g0 = (m0 >> 4) + wh * HR;

  f32x4 acc[HR][5];
#pragma unroll
  for (int rt = 0; rt < HR; rt++)
#pragma unroll
    for (int nt = 0; nt < 5; nt++) acc[rt][nt] = (f32x4){0.f, 0.f, 0.f, 0.f};

#pragma unroll 2
  for (int ks = 0; ks < 19; ks++) {
    short8 a[HR];
#pragma unroll
    for (int rt = 0; rt < HR; rt++)
      a[rt] = *(const short8*)(hin_f +
          (((size_t)(g0 + rt) * 19 + ks) * 64 + l) * 8);
#pragma unroll
    for (int nt = 0; nt < 5; nt++) {
      short8 b = *(const short8*)(Wf +
          ((size_t)((5 * wg + nt) * 19 + ks) * 64 + l) * 8);
#pragma unroll
      for (int rt = 0; rt < HR; rt++)
        acc[rt][nt] = __builtin_amdgcn_mfma_f32_16x16x32_bf16(
            a[rt], b, acc[rt][nt], 0, 0, 0);
    }
  }

#pragma unroll
  for (int nt = 0; nt < 5; nt++) {
    int n = wg * 80 + nt * 16 + q;
    float wb = (n < E_) ? Wb[n] : 0.f;
    if (n < 304) {
#pragma unroll
      for (int rt = 0; rt < HR; rt++)
#pragma unroll
        for (int j = 0; j < 4; j++) {
          int rl = (wh * HR + rt) * 16 + half * 4 + j;
          HSROW(hsO, rl)[n] = f2bs(fmaxf(acc[rt][nt][j] + wb, 0.f));
        }
    }
  }
  __syncthreads();

  // frag-store: RT/2 g-tiles of 32 rows per block
  for (int i = tid; i < (RT / 2) * 1216; i += 512) {
    int gl = i / 1216, rem = i % 1216;
    int ks = rem >> 6, ll = rem & 63;
    int qq = ll & 15, hh = ll >> 4;
    int k0 = ks * 32 + hh * 8;
    int sel = k0 >= 304 ? 1 : 0;
    int e = k0 - 304 * sel;
    int lr = 2 * (gl * 16 + qq) + sel;
    short8 v = *(const short8*)&HSROW(hsO, lr)[e];
    *(short8*)(hout_f +
               (((size_t)((m0 >> 5) + gl) * 19 + ks) * 64 + ll) * 8) = v;
  }
  // projection: waves 0..RT-1, rows [16w, 16w+16)
  if (w < RT) {
    f32x4 pacc = (f32x4){0.f, 0.f, 0.f, 0.f};
#pragma unroll
    for (int ks = 0; ks < 10; ks++) {
      int k0 = ks * 32 + half * 8;
      short8 a = PROJ_A(HSROW(hsO, 16 * w + q), ks, k0);
      short8 b = *(const short8*)(Ppf + ((size_t)ks * 64 + l) * 8);
      pacc = __builtin_amdgcn_mfma_f32_16x16x32_bf16(a, b, pacc, 0, 0, 0);
    }
    if (q < C_) {
      float pb = Pb[q];
#pragma unroll
      for (int j = 0; j < 4; j++) {
        size_t m = m0 + w * 16 + half * 4 + j;
        size_t b_ = m >> nshift;
        size_t n = m & (((size_t)1 << nshift) - 1);
        out[((size_t)b_ * NODES + node_off + n) * C_ + q] = pacc[j] + pb;
      }
    }
  }
}

// ---------------------------------------------------------------------------
extern "C" void kernel_launch(void* const* d_in, const int* in_sizes, int n_in,
                              void* d_out, int out_size, void* d_ws,
                              size_t ws_size, hipStream_t stream) {
  const int* wid = (const int*)d_in[0];
  const float* emb = (const float*)d_in[1];
  const float* Ww = (const float*)d_in[2];
  const float* Wb = (const float*)d_in[3];
  const float* Pw = (const float*)d_in[4];
  const float* Pb = (const float*)d_in[5];
  float* out = (float*)d_out;
  int V = in_sizes[1] / E_;  // 50000

  bf16* hA = (bf16*)d_ws;                     // h1f, h3f, h5f, h7f, h9f
  bf16* hB = hA + (size_t)B_ * 512 * 304;     // h2f, h4f, h6f, h8f, h10f
  bf16* Wf = hB + (size_t)B_ * 256 * 304;
  bf16* Pqf = Wf + (size_t)20 * 19 * 512;
  bf16* Ppf = Pqf + (size_t)2 * 19 * 512;
  bf16* T = Ppf + (size_t)10 * 512;           // V * 304 (30.4 MB)

  int tchunks = V * 38;
  prep_k<<<(tchunks + 255) / 256, 256, 0, stream>>>(emb, Ww, Pw, T, Wf, Pqf,
                                                    Ppf, V);
  fused_l1_k<<<1024, 512, 0, stream>>>(wid, T, Wf, Wb, Pqf, Ppf, Pb, hA, out);
  // lvl2..5: M = 32768, 16384, 8192, 4096
  combine_k<4><<<512, 512, 0, stream>>>(hA, Wf, Wb, Ppf, Pb, hB, out, 1536, 8);
  combine_k<4><<<256, 512, 0, stream>>>(hB, Wf, Wb, Ppf, Pb, hA, out, 1792, 7);
  combine_k<2><<<256, 512, 0, stream>>>(hA, Wf, Wb, Ppf, Pb, hB, out, 1920, 6);
  combine_k<2><<<128, 512, 0, stream>>>(hB, Wf, Wb, Ppf, Pb, hA, out, 1984, 5);
  // lvl6..10: M = 2048, 1024, 512, 256, 128
  combine_k<2><<<64, 512, 0, stream>>>(hA, Wf, Wb, Ppf, Pb, hB, out, 2016, 4);
  combine_k<2><<<32, 512, 0, stream>>>(hB, Wf, Wb, Ppf, Pb, hA, out, 2032, 3);
  combine_k<2><<<16, 512, 0, stream>>>(hA, Wf, Wb, Ppf, Pb, hB, out, 2040, 2);
  combine_k<2><<<8, 512, 0, stream>>>(hB, Wf, Wb, Ppf, Pb, hA, out, 2044, 1);
  combine_k<2><<<4, 512, 0, stream>>>(hA, Wf, Wb, Ppf, Pb, hB, out, 2046, 0);
}